// Round 3
// baseline (416.792 us; speedup 1.0000x reference)
//
#include <hip/hip_runtime.h>
#include <hip/hip_bf16.h>

typedef unsigned short u16;
typedef __attribute__((ext_vector_type(8))) short short8;
typedef __attribute__((ext_vector_type(4))) float f32x4;

__device__ __forceinline__ float bf2f(u16 u){
  union { unsigned int i; float f; } c; c.i = ((unsigned int)u) << 16; return c.f;
}
__device__ __forceinline__ u16 f2bf(float f){
  union { float f; unsigned int i; } c; c.f = f;
  unsigned int x = c.i;
  return (u16)((x + 0x7FFFu + ((x >> 16) & 1u)) >> 16);  // RNE
}

// int64-aware edge fetch (values < 2^31, little-endian: low word is the value)
__device__ __forceinline__ int edge_get(const int* __restrict__ e32, int i64, int e, int c){
  int idx = 2 * e + c;
  return i64 ? e32[2 * idx] : e32[idx];
}

// ---------------------------------------------------------------------------
// Dtype detection. flags[0]=1 if float inputs are fp32 (else bf16).
// flags[1]=1 if edges are int64 (else int32).
// Evidence so far (R1 NaN with bf16 interp, R2 finite with detection):
// inputs ARE fp32. Detection kept as cheap insurance.
// ---------------------------------------------------------------------------
__global__ void detect_kernel(const u16* __restrict__ lig16,
                              const int* __restrict__ e32, int* __restrict__ flags)
{
  int lane = threadIdx.x;
  int cnt = 0, nz = 0;
  #pragma unroll
  for (int j = 0; j < 4; j++){
    u16 u = lig16[(lane * 4 + j) * 2];
    int ex = (u >> 7) & 0xFF;
    if (ex >= 96 && ex < 160) cnt++;
    if (e32[(lane * 4 + j) * 2 + 1] != 0) nz++;
  }
  #pragma unroll
  for (int off = 1; off < 64; off <<= 1){
    cnt += __shfl_xor(cnt, off);
    nz  += __shfl_xor(nz, off);
  }
  if (lane == 0){
    flags[0] = (cnt < 128) ? 1 : 0;
    flags[1] = (nz == 0) ? 1 : 0;
  }
}

// ---------------------------------------------------------------------------
// GEMM: C[M,128] = A[M,128] @ W[128,128] + b. Up to 3 weight sets via
// blockIdx.y. MFMA 16x16x32 bf16, 64x128 block tile.
// a_force_bf16: A is our bf16 workspace regardless of flags (final GEMMs).
// final_out && flags[0]: write fp32 to Cf (d_out); else bf16 to Cb.
// ---------------------------------------------------------------------------
__global__ __launch_bounds__(256) void gemm_qkv(
    const void* __restrict__ A, int M,
    const void* __restrict__ W0, const void* __restrict__ W1, const void* __restrict__ W2,
    const void* __restrict__ b0, const void* __restrict__ b1, const void* __restrict__ b2,
    u16* __restrict__ C0b, u16* __restrict__ C1b, u16* __restrict__ C2b,
    float* __restrict__ C0f, float* __restrict__ C1f, float* __restrict__ C2f,
    int a_force_bf16, int final_out, const int* __restrict__ flags)
{
  __shared__ u16 As[64][136];
  __shared__ u16 Ws[128][136];
  __shared__ float biasf[128];

  int tid = threadIdx.x;
  int F = flags[0];
  int AF = a_force_bf16 ? 0 : F;   // A operand dtype: 1=fp32, 0=bf16
  int mat = blockIdx.y;
  const void* W  = (mat == 0) ? W0 : ((mat == 1) ? W1 : W2);
  const void* bb = (mat == 0) ? b0 : ((mat == 1) ? b1 : b2);
  u16*   Cb      = (mat == 0) ? C0b : ((mat == 1) ? C1b : C2b);
  float* Cf      = (mat == 0) ? C0f : ((mat == 1) ? C1f : C2f);
  int m0 = blockIdx.x * 64;

  // Stage A tile
  if (AF){
    const float* Af = (const float*)A;
    #pragma unroll
    for (int j = 0; j < 8; j++){
      int idx = tid + j * 256;
      int m = idx >> 5, k4 = idx & 31;
      int row = m0 + m;
      float4 v = make_float4(0.f, 0.f, 0.f, 0.f);
      if (row < M) v = *(const float4*)&Af[row * 128 + k4 * 4];
      ushort4 o; o.x = f2bf(v.x); o.y = f2bf(v.y); o.z = f2bf(v.z); o.w = f2bf(v.w);
      *(ushort4*)&As[m][k4 * 4] = o;
    }
  } else {
    const u16* Au = (const u16*)A;
    #pragma unroll
    for (int j = 0; j < 8; j++){
      int idx = tid + j * 256;
      int m = idx >> 5, k4 = idx & 31;
      int row = m0 + m;
      ushort4 val = make_ushort4(0, 0, 0, 0);
      if (row < M) val = *(const ushort4*)&Au[row * 128 + k4 * 4];
      *(ushort4*)&As[m][k4 * 4] = val;
    }
  }
  // Stage W transposed: Ws[n][k]
  if (F){
    const float* Wf = (const float*)W;
    #pragma unroll
    for (int j = 0; j < 64; j++){
      int idx = tid + j * 256;
      Ws[idx & 127][idx >> 7] = f2bf(Wf[idx]);
    }
  } else {
    const u16* Wu = (const u16*)W;
    #pragma unroll
    for (int j = 0; j < 64; j++){
      int idx = tid + j * 256;
      Ws[idx & 127][idx >> 7] = Wu[idx];
    }
  }
  if (tid < 128) biasf[tid] = F ? ((const float*)bb)[tid] : bf2f(((const u16*)bb)[tid]);
  __syncthreads();

  int wave = tid >> 6, lane = tid & 63;
  int quad = lane >> 4, ml = lane & 15;

  short8 af[4];
  #pragma unroll
  for (int kk = 0; kk < 4; kk++)
    af[kk] = *(const short8*)&As[wave * 16 + ml][kk * 32 + quad * 8];

  f32x4 acc[8];
  #pragma unroll
  for (int nt = 0; nt < 8; nt++) acc[nt] = (f32x4){0.f, 0.f, 0.f, 0.f};

  #pragma unroll
  for (int nt = 0; nt < 8; nt++){
    #pragma unroll
    for (int kk = 0; kk < 4; kk++){
      short8 bfr = *(const short8*)&Ws[nt * 16 + ml][kk * 32 + quad * 8];
      acc[nt] = __builtin_amdgcn_mfma_f32_16x16x32_bf16(af[kk], bfr, acc[nt], 0, 0, 0);
    }
  }

  int f32out = final_out && F;
  #pragma unroll
  for (int nt = 0; nt < 8; nt++){
    #pragma unroll
    for (int r = 0; r < 4; r++){
      int row = m0 + wave * 16 + quad * 4 + r;
      if (row < M){
        int col = nt * 16 + ml;
        float v = acc[nt][r] + biasf[col];
        if (f32out) Cf[row * 128 + col] = v;
        else        Cb[row * 128 + col] = f2bf(v);
      }
    }
  }
}

// ---------------------------------------------------------------------------
// RBF bias: ebias[E,8] = fp32(attr[E,16] @ Wr[16,8] + br)
// ---------------------------------------------------------------------------
__global__ __launch_bounds__(256) void rbf_kernel(
    const void* __restrict__ attr, const void* __restrict__ Wr,
    const void* __restrict__ br, float* __restrict__ ebias, int E_,
    const int* __restrict__ flags)
{
  __shared__ float w[16][8];
  __shared__ float b[8];
  int tid = threadIdx.x;
  int F = flags[0];
  if (tid < 128) w[tid >> 3][tid & 7] = F ? ((const float*)Wr)[tid] : bf2f(((const u16*)Wr)[tid]);
  if (tid < 8)   b[tid] = F ? ((const float*)br)[tid] : bf2f(((const u16*)br)[tid]);
  __syncthreads();
  int e = blockIdx.x * 256 + tid;
  if (e >= E_) return;
  float a[16];
  if (F){
    const float* af = (const float*)attr;
    #pragma unroll
    for (int j = 0; j < 4; j++){
      float4 t = *(const float4*)&af[e * 16 + j * 4];
      a[4*j] = t.x; a[4*j+1] = t.y; a[4*j+2] = t.z; a[4*j+3] = t.w;
    }
  } else {
    const u16* au = (const u16*)attr;
    #pragma unroll
    for (int j = 0; j < 4; j++){
      ushort4 t = *(const ushort4*)&au[e * 16 + j * 4];
      a[4*j] = bf2f(t.x); a[4*j+1] = bf2f(t.y); a[4*j+2] = bf2f(t.z); a[4*j+3] = bf2f(t.w);
    }
  }
  #pragma unroll
  for (int hh = 0; hh < 8; hh++){
    float s = b[hh];
    #pragma unroll
    for (int r = 0; r < 16; r++) s += a[r] * w[r][hh];
    ebias[e * 8 + hh] = s;
  }
}

// ---------------------------------------------------------------------------
// CSR build: count -> scan(3 kernels) -> scatter. Combined [lig | prot].
// ---------------------------------------------------------------------------
__global__ __launch_bounds__(256) void count_kernel(
    const int* __restrict__ edges, const int* __restrict__ ls_p,
    const int* __restrict__ ps_p, int* __restrict__ cnt, int nlig, int E_,
    const int* __restrict__ flags)
{
  int e = blockIdx.x * 256 + threadIdx.x;
  if (e >= E_) return;
  int I64 = flags[1];
  int dl = edge_get(edges, I64, e, 0) - ls_p[0];
  int dp = edge_get(edges, I64, e, 1) - ps_p[0];
  atomicAdd(&cnt[dl], 1);
  atomicAdd(&cnt[nlig + dp], 1);
}

__global__ __launch_bounds__(256) void scan_blocksum(
    const int* __restrict__ cnt, int* __restrict__ bsum, int n)
{
  __shared__ int red[4];
  int tid = threadIdx.x;
  int i = blockIdx.x * 256 + tid;
  int v = (i < n) ? cnt[i] : 0;
  #pragma unroll
  for (int off = 1; off < 64; off <<= 1) v += __shfl_xor(v, off);
  if ((tid & 63) == 0) red[tid >> 6] = v;
  __syncthreads();
  if (tid == 0) bsum[blockIdx.x] = red[0] + red[1] + red[2] + red[3];
}

__global__ __launch_bounds__(512) void scan_bsum(
    int* __restrict__ bsum, int* __restrict__ boff, int nb)
{
  __shared__ int buf[512];
  int tid = threadIdx.x;
  int v = (tid < nb) ? bsum[tid] : 0;
  buf[tid] = v; __syncthreads();
  for (int off = 1; off < 512; off <<= 1){
    int t = (tid >= off) ? buf[tid - off] : 0;
    __syncthreads();
    buf[tid] += t;
    __syncthreads();
  }
  if (tid < nb) boff[tid] = buf[tid] - v;   // exclusive
}

__global__ __launch_bounds__(256) void scan_final(
    const int* __restrict__ cnt, const int* __restrict__ boff,
    int* __restrict__ offs, int* __restrict__ cursor, int n)
{
  __shared__ int buf[256];
  int tid = threadIdx.x;
  int i = blockIdx.x * 256 + tid;
  int v = (i < n) ? cnt[i] : 0;
  buf[tid] = v; __syncthreads();
  for (int off = 1; off < 256; off <<= 1){
    int t = (tid >= off) ? buf[tid - off] : 0;
    __syncthreads();
    buf[tid] += t;
    __syncthreads();
  }
  int excl = buf[tid] - v + boff[blockIdx.x];
  if (i < n){
    offs[i] = excl;
    cursor[i] = excl;
    if (i == n - 1) offs[n] = excl + v;
  }
}

__global__ __launch_bounds__(256) void scatter_kernel(
    const int* __restrict__ edges, const int* __restrict__ ls_p,
    const int* __restrict__ ps_p, int* __restrict__ cursor,
    int* __restrict__ sorted_eid, int nlig, int E_,
    const int* __restrict__ flags)
{
  int e = blockIdx.x * 256 + threadIdx.x;
  if (e >= E_) return;
  int I64 = flags[1];
  int dl = edge_get(edges, I64, e, 0) - ls_p[0];
  int dp = edge_get(edges, I64, e, 1) - ps_p[0];
  int p1 = atomicAdd(&cursor[dl], 1);        sorted_eid[p1] = e;
  int p2 = atomicAdd(&cursor[nlig + dp], 1); sorted_eid[p2] = e;
}

// ---------------------------------------------------------------------------
// Attention: one wave per destination node, online softmax.
// 64 lanes = 8 heads x 8 lanes; lane covers dims {2*lane, 2*lane+1} of 128.
// ---------------------------------------------------------------------------
__global__ __launch_bounds__(256) void attn_kernel(
    const u16* __restrict__ qn, const u16* __restrict__ kn, const u16* __restrict__ vn,
    const int* __restrict__ sorted_eid, const int* __restrict__ offs, int offs_base,
    const int* __restrict__ edges, int src_col, const int* __restrict__ src_start_p,
    const float* __restrict__ ebias, u16* __restrict__ agg, int n_dst,
    const int* __restrict__ flags)
{
  int wave = threadIdx.x >> 6, lane = threadIdx.x & 63;
  int node = blockIdx.x * 4 + wave;
  if (node >= n_dst) return;
  int h = lane >> 3;
  int I64 = flags[1];
  int src_start = src_start_p[0];

  ushort2 qu = *(const ushort2*)&qn[node * 128 + lane * 2];
  float q0 = bf2f(qu.x), q1 = bf2f(qu.y);

  int beg = offs[offs_base + node], end = offs[offs_base + node + 1];
  float m = -INFINITY, l = 0.f, a0 = 0.f, a1 = 0.f;

  for (int i = beg; i < end; i++){
    int e = sorted_eid[i];
    int src = edge_get(edges, I64, e, src_col) - src_start;
    ushort2 ku = *(const ushort2*)&kn[src * 128 + lane * 2];
    ushort2 vu = *(const ushort2*)&vn[src * 128 + lane * 2];
    float part = q0 * bf2f(ku.x) + q1 * bf2f(ku.y);
    part += __shfl_xor(part, 1);
    part += __shfl_xor(part, 2);
    part += __shfl_xor(part, 4);          // per-head 16-dim dot done
    float logit = part * 0.25f + ebias[e * 8 + h];   // SCALE = 16^-0.5
    float nm = fmaxf(m, logit);
    float alpha = __expf(m - nm);         // exp(-inf)=0 on first edge
    float p = __expf(logit - nm);
    a0 = a0 * alpha + p * bf2f(vu.x);
    a1 = a1 * alpha + p * bf2f(vu.y);
    l = l * alpha + p;
    m = nm;
  }
  float inv = 1.f / (l + 1e-8f);          // empty segment -> 0, matches ref
  ushort2 o; o.x = f2bf(a0 * inv); o.y = f2bf(a1 * inv);
  *(ushort2*)&agg[node * 128 + lane * 2] = o;
}

// ---------------------------------------------------------------------------
extern "C" void kernel_launch(void* const* d_in, const int* in_sizes, int n_in,
                              void* d_out, int out_size, void* d_ws, size_t ws_size,
                              hipStream_t stream)
{
  const void* ligand_x  = d_in[0];
  const void* protein_x = d_in[1];
  const int* edges      = (const int*)d_in[2];
  const void* attr      = d_in[3];
  const void* Wq = d_in[4];  const void* bq = d_in[5];
  const void* Wk = d_in[6];  const void* bk = d_in[7];
  const void* Wv = d_in[8];  const void* bv = d_in[9];
  const void* Wo = d_in[10]; const void* bo = d_in[11];
  const void* Wr = d_in[12]; const void* br = d_in[13];
  const int* ls_p = (const int*)d_in[14];
  const int* ps_p = (const int*)d_in[15];

  const int nlig = in_sizes[0] / 128;
  const int nprot = in_sizes[1] / 128;
  const int E = in_sizes[2] / 2;
  const int ntot = nlig + nprot;

  // workspace carve-up (256B aligned)
  char* w = (char*)d_ws;
  size_t off = 0;
  auto alloc = [&](size_t bytes) -> void* {
    void* p = w + off;
    off = (off + bytes + 255) & ~(size_t)255;
    return p;
  };
  int* flags = (int*)alloc(256);
  u16* q_l = (u16*)alloc((size_t)nlig * 128 * 2);
  u16* k_l = (u16*)alloc((size_t)nlig * 128 * 2);
  u16* v_l = (u16*)alloc((size_t)nlig * 128 * 2);
  u16* q_p = (u16*)alloc((size_t)nprot * 128 * 2);
  u16* k_p = (u16*)alloc((size_t)nprot * 128 * 2);
  u16* v_p = (u16*)alloc((size_t)nprot * 128 * 2);
  u16* agg_l = (u16*)alloc((size_t)nlig * 128 * 2);
  u16* agg_p = (u16*)alloc((size_t)nprot * 128 * 2);
  float* ebias = (float*)alloc((size_t)E * 8 * 4);
  int* cnt    = (int*)alloc((size_t)ntot * 4);
  int* offs   = (int*)alloc((size_t)(ntot + 1) * 4);
  int* cursor = (int*)alloc((size_t)ntot * 4);
  int* bsum   = (int*)alloc(512 * 4);
  int* boff   = (int*)alloc(512 * 4);
  int* sorted = (int*)alloc((size_t)2 * E * 4);
  (void)ws_size; (void)n_in; (void)out_size;

  u16* out_b      = (u16*)d_out;
  u16* out_prot_b = out_b + (size_t)nlig * 128;
  float* out_f      = (float*)d_out;
  float* out_prot_f = out_f + (size_t)nlig * 128;

  const int mb_l = (nlig + 63) / 64;
  const int mb_p = (nprot + 63) / 64;
  const int eb = (E + 255) / 256;
  const int nb = (ntot + 255) / 256;

  // 0. dtype detection
  detect_kernel<<<1, 64, 0, stream>>>((const u16*)ligand_x, edges, flags);

  // 1. projections (q/k/v fused per input array); A dtype follows flags
  gemm_qkv<<<dim3(mb_l, 3), 256, 0, stream>>>(ligand_x, nlig, Wq, Wk, Wv, bq, bk, bv,
      q_l, k_l, v_l, nullptr, nullptr, nullptr, /*a_force_bf16=*/0, /*final=*/0, flags);
  gemm_qkv<<<dim3(mb_p, 3), 256, 0, stream>>>(protein_x, nprot, Wq, Wk, Wv, bq, bk, bv,
      q_p, k_p, v_p, nullptr, nullptr, nullptr, 0, 0, flags);

  // 2. rbf bias
  rbf_kernel<<<eb, 256, 0, stream>>>(attr, Wr, br, ebias, E, flags);

  // 3. CSR build
  hipMemsetAsync(cnt, 0, (size_t)ntot * 4, stream);
  count_kernel<<<eb, 256, 0, stream>>>(edges, ls_p, ps_p, cnt, nlig, E, flags);
  scan_blocksum<<<nb, 256, 0, stream>>>(cnt, bsum, ntot);
  scan_bsum<<<1, 512, 0, stream>>>(bsum, boff, nb);
  scan_final<<<nb, 256, 0, stream>>>(cnt, boff, offs, cursor, ntot);
  scatter_kernel<<<eb, 256, 0, stream>>>(edges, ls_p, ps_p, cursor, sorted, nlig, E, flags);

  // 4. attention (one wave per destination node)
  attn_kernel<<<(nlig + 3) / 4, 256, 0, stream>>>(q_l, k_p, v_p, sorted, offs, 0,
      edges, 1, ps_p, ebias, agg_l, nlig, flags);
  attn_kernel<<<(nprot + 3) / 4, 256, 0, stream>>>(q_p, k_l, v_l, sorted, offs, nlig,
      edges, 0, ls_p, ebias, agg_p, nprot, flags);

  // 5. output projection into d_out. A = bf16 workspace ALWAYS (the R2 bug:
  //    it was read as fp32 when flags said fp32). Output dtype follows flags.
  gemm_qkv<<<dim3(mb_l, 1), 256, 0, stream>>>(agg_l, nlig, Wo, Wo, Wo, bo, bo, bo,
      out_b, out_b, out_b, out_f, out_f, out_f, /*a_force_bf16=*/1, /*final=*/1, flags);
  gemm_qkv<<<dim3(mb_p, 1), 256, 0, stream>>>(agg_p, nprot, Wo, Wo, Wo, bo, bo, bo,
      out_prot_b, out_prot_b, out_prot_b, out_prot_f, out_prot_f, out_prot_f, 1, 1, flags);
}

// Round 4
// 378.391 us; speedup vs baseline: 1.1015x; 1.1015x over previous
//
#include <hip/hip_runtime.h>
#include <hip/hip_bf16.h>

typedef unsigned short u16;
typedef __attribute__((ext_vector_type(8))) short short8;
typedef __attribute__((ext_vector_type(4))) float f32x4;

__device__ __forceinline__ float bf2f(u16 u){
  union { unsigned int i; float f; } c; c.i = ((unsigned int)u) << 16; return c.f;
}
__device__ __forceinline__ u16 f2bf(float f){
  union { float f; unsigned int i; } c; c.f = f;
  unsigned int x = c.i;
  return (u16)((x + 0x7FFFu + ((x >> 16) & 1u)) >> 16);  // RNE
}

// int64-aware edge fetch (values < 2^31, little-endian: low word is the value)
__device__ __forceinline__ int edge_get(const int* __restrict__ e32, int i64, int e, int c){
  int idx = 2 * e + c;
  return i64 ? e32[2 * idx] : e32[idx];
}

// ---------------------------------------------------------------------------
// Dtype detection (R1/R2 evidence: inputs ARE fp32, but keep as insurance).
// flags[0]=1 -> float inputs fp32 (else bf16); flags[1]=1 -> edges int64.
// ---------------------------------------------------------------------------
__global__ void detect_kernel(const u16* __restrict__ lig16,
                              const int* __restrict__ e32, int* __restrict__ flags)
{
  int lane = threadIdx.x;
  int cnt = 0, nz = 0;
  #pragma unroll
  for (int j = 0; j < 4; j++){
    u16 u = lig16[(lane * 4 + j) * 2];
    int ex = (u >> 7) & 0xFF;
    if (ex >= 96 && ex < 160) cnt++;
    if (e32[(lane * 4 + j) * 2 + 1] != 0) nz++;
  }
  #pragma unroll
  for (int off = 1; off < 64; off <<= 1){
    cnt += __shfl_xor(cnt, off);
    nz  += __shfl_xor(nz, off);
  }
  if (lane == 0){
    flags[0] = (cnt < 128) ? 1 : 0;
    flags[1] = (nz == 0) ? 1 : 0;
  }
}

// ---------------------------------------------------------------------------
// prep_w: Wt[mat][n][k] = bf16(W[mat][k][n]) for Wq,Wk,Wv,Wo; biases -> fp32.
// One block per mat.
// ---------------------------------------------------------------------------
__global__ __launch_bounds__(256) void prep_w(
    const void* __restrict__ Wq, const void* __restrict__ Wk,
    const void* __restrict__ Wv, const void* __restrict__ Wo,
    const void* __restrict__ bq, const void* __restrict__ bk,
    const void* __restrict__ bv, const void* __restrict__ bo,
    u16* __restrict__ Wt, float* __restrict__ biasP, const int* __restrict__ flags)
{
  int mat = blockIdx.x, tid = threadIdx.x;
  const void* W = (mat == 0) ? Wq : (mat == 1) ? Wk : (mat == 2) ? Wv : Wo;
  const void* b = (mat == 0) ? bq : (mat == 1) ? bk : (mat == 2) ? bv : bo;
  int F = flags[0];
  u16* dst = Wt + mat * 16384;
  #pragma unroll 4
  for (int j = 0; j < 64; j++){
    int idx = tid + j * 256;            // k = idx>>7, n = idx&127
    u16 w = F ? f2bf(((const float*)W)[idx]) : ((const u16*)W)[idx];
    dst[(idx & 127) * 128 + (idx >> 7)] = w;
  }
  if (tid < 128)
    biasP[mat * 128 + tid] = F ? ((const float*)b)[tid] : bf2f(((const u16*)b)[tid]);
}

// ---------------------------------------------------------------------------
// gemm_multi: two input regions (ligand rows then protein rows) x nm weight
// mats. C[orow..][128] = A[m..][128] @ Wt[mat]^T + bias. A staged once per
// block; Wt re-staged per mat (bf16, 8 x 16B iters). MFMA 16x16x32 bf16.
// ---------------------------------------------------------------------------
__global__ __launch_bounds__(256) void gemm_multi(
    const void* __restrict__ A0, int M0, const void* __restrict__ A1, int M1, int mb0,
    const u16* __restrict__ Wt, const float* __restrict__ biasP, int wbase, int nm,
    u16* __restrict__ O0b, u16* __restrict__ O1b, u16* __restrict__ O2b,
    float* __restrict__ O0f,
    int a_force_bf16, int final_out, const int* __restrict__ flags)
{
  __shared__ u16 As[64][136];
  __shared__ u16 Ws[128][136];

  int tid = threadIdx.x;
  int F = flags[0];
  int AF = a_force_bf16 ? 0 : F;       // A dtype: 1=fp32, 0=bf16
  int xb = blockIdx.x;
  const void* A; int M, m0, orow;
  if (xb < mb0){ A = A0; M = M0; m0 = xb * 64;          orow = m0; }
  else         { A = A1; M = M1; m0 = (xb - mb0) * 64;  orow = M0 + m0; }

  // Stage A tile (64 x 128)
  if (AF){
    const float* Af = (const float*)A;
    #pragma unroll
    for (int j = 0; j < 8; j++){
      int idx = tid + j * 256;          // m = idx>>5, k4 = idx&31
      int m = idx >> 5, k4 = idx & 31;
      float4 v = make_float4(0.f, 0.f, 0.f, 0.f);
      if (m0 + m < M) v = *(const float4*)&Af[(size_t)(m0 + m) * 128 + k4 * 4];
      ushort4 o; o.x = f2bf(v.x); o.y = f2bf(v.y); o.z = f2bf(v.z); o.w = f2bf(v.w);
      *(ushort4*)&As[m][k4 * 4] = o;
    }
  } else {
    const u16* Au = (const u16*)A;
    #pragma unroll
    for (int j = 0; j < 8; j++){
      int idx = tid + j * 256;
      int m = idx >> 5, k4 = idx & 31;
      ushort4 v = make_ushort4(0, 0, 0, 0);
      if (m0 + m < M) v = *(const ushort4*)&Au[(size_t)(m0 + m) * 128 + k4 * 4];
      *(ushort4*)&As[m][k4 * 4] = v;
    }
  }
  // Stage Wt[wbase+0]: 16384 u16 = 2048 x 16B
  {
    const u16* Wsrc = Wt + (size_t)(wbase) * 16384;
    #pragma unroll
    for (int j = 0; j < 8; j++){
      int idx = tid + j * 256;          // n = idx>>4, k8 = idx&15
      *(short8*)&Ws[idx >> 4][(idx & 15) * 8] = *(const short8*)&Wsrc[idx * 8];
    }
  }
  __syncthreads();

  int wave = tid >> 6, lane = tid & 63;
  int quad = lane >> 4, ml = lane & 15;

  short8 af[4];
  #pragma unroll
  for (int kk = 0; kk < 4; kk++)
    af[kk] = *(const short8*)&As[wave * 16 + ml][kk * 32 + quad * 8];

  int f32out = final_out && F;

  for (int mat = 0; mat < nm; mat++){
    f32x4 acc[8];
    #pragma unroll
    for (int nt = 0; nt < 8; nt++) acc[nt] = (f32x4){0.f, 0.f, 0.f, 0.f};

    #pragma unroll
    for (int nt = 0; nt < 8; nt++){
      #pragma unroll
      for (int kk = 0; kk < 4; kk++){
        short8 bfr = *(const short8*)&Ws[nt * 16 + ml][kk * 32 + quad * 8];
        acc[nt] = __builtin_amdgcn_mfma_f32_16x16x32_bf16(af[kk], bfr, acc[nt], 0, 0, 0);
      }
    }

    const float* bp = biasP + (size_t)(wbase + mat) * 128;
    u16* Cb = (mat == 0) ? O0b : ((mat == 1) ? O1b : O2b);
    #pragma unroll
    for (int nt = 0; nt < 8; nt++){
      float bcol = bp[nt * 16 + ml];
      #pragma unroll
      for (int r = 0; r < 4; r++){
        int lr = wave * 16 + quad * 4 + r;
        if (m0 + lr < M){
          size_t oi = (size_t)(orow + lr) * 128 + nt * 16 + ml;
          float v = acc[nt][r] + bcol;
          if (f32out) O0f[oi] = v;
          else        Cb[oi]  = f2bf(v);
        }
      }
    }

    if (mat + 1 < nm){
      __syncthreads();                  // all waves done reading Ws
      const u16* Wsrc = Wt + (size_t)(wbase + mat + 1) * 16384;
      #pragma unroll
      for (int j = 0; j < 8; j++){
        int idx = tid + j * 256;
        *(short8*)&Ws[idx >> 4][(idx & 15) * 8] = *(const short8*)&Wsrc[idx * 8];
      }
      __syncthreads();
    }
  }
}

// ---------------------------------------------------------------------------
// RBF bias: ebias[E,8] = fp32(attr[E,16] @ Wr[16,8] + br)
// ---------------------------------------------------------------------------
__global__ __launch_bounds__(256) void rbf_kernel(
    const void* __restrict__ attr, const void* __restrict__ Wr,
    const void* __restrict__ br, float* __restrict__ ebias, int E_,
    const int* __restrict__ flags)
{
  __shared__ float w[16][8];
  __shared__ float b[8];
  int tid = threadIdx.x;
  int F = flags[0];
  if (tid < 128) w[tid >> 3][tid & 7] = F ? ((const float*)Wr)[tid] : bf2f(((const u16*)Wr)[tid]);
  if (tid < 8)   b[tid] = F ? ((const float*)br)[tid] : bf2f(((const u16*)br)[tid]);
  __syncthreads();
  int e = blockIdx.x * 256 + tid;
  if (e >= E_) return;
  float a[16];
  if (F){
    const float* af = (const float*)attr;
    #pragma unroll
    for (int j = 0; j < 4; j++){
      float4 t = *(const float4*)&af[e * 16 + j * 4];
      a[4*j] = t.x; a[4*j+1] = t.y; a[4*j+2] = t.z; a[4*j+3] = t.w;
    }
  } else {
    const u16* au = (const u16*)attr;
    #pragma unroll
    for (int j = 0; j < 4; j++){
      ushort4 t = *(const ushort4*)&au[e * 16 + j * 4];
      a[4*j] = bf2f(t.x); a[4*j+1] = bf2f(t.y); a[4*j+2] = bf2f(t.z); a[4*j+3] = bf2f(t.w);
    }
  }
  #pragma unroll
  for (int hh = 0; hh < 8; hh++){
    float s = b[hh];
    #pragma unroll
    for (int r = 0; r < 16; r++) s += a[r] * w[r][hh];
    ebias[e * 8 + hh] = s;
  }
}

// ---------------------------------------------------------------------------
// CSR build over combined node space [lig | prot].
// ---------------------------------------------------------------------------
__global__ __launch_bounds__(256) void count_kernel(
    const int* __restrict__ edges, const int* __restrict__ ls_p,
    const int* __restrict__ ps_p, int* __restrict__ cnt, int nlig, int E_,
    const int* __restrict__ flags)
{
  int e = blockIdx.x * 256 + threadIdx.x;
  if (e >= E_) return;
  int I64 = flags[1];
  int dl = edge_get(edges, I64, e, 0) - ls_p[0];
  int dp = edge_get(edges, I64, e, 1) - ps_p[0];
  atomicAdd(&cnt[dl], 1);
  atomicAdd(&cnt[nlig + dp], 1);
}

__global__ __launch_bounds__(256) void scan_blocksum(
    const int* __restrict__ cnt, int* __restrict__ bsum, int n)
{
  __shared__ int red[4];
  int tid = threadIdx.x;
  int i = blockIdx.x * 256 + tid;
  int v = (i < n) ? cnt[i] : 0;
  #pragma unroll
  for (int off = 1; off < 64; off <<= 1) v += __shfl_xor(v, off);
  if ((tid & 63) == 0) red[tid >> 6] = v;
  __syncthreads();
  if (tid == 0) bsum[blockIdx.x] = red[0] + red[1] + red[2] + red[3];
}

__global__ __launch_bounds__(512) void scan_bsum(
    int* __restrict__ bsum, int* __restrict__ boff, int nb)
{
  __shared__ int buf[512];
  int tid = threadIdx.x;
  int v = (tid < nb) ? bsum[tid] : 0;
  buf[tid] = v; __syncthreads();
  for (int off = 1; off < 512; off <<= 1){
    int t = (tid >= off) ? buf[tid - off] : 0;
    __syncthreads();
    buf[tid] += t;
    __syncthreads();
  }
  if (tid < nb) boff[tid] = buf[tid] - v;   // exclusive
}

__global__ __launch_bounds__(256) void scan_final(
    const int* __restrict__ cnt, const int* __restrict__ boff,
    int* __restrict__ offs, int* __restrict__ cursor, int n)
{
  __shared__ int buf[256];
  int tid = threadIdx.x;
  int i = blockIdx.x * 256 + tid;
  int v = (i < n) ? cnt[i] : 0;
  buf[tid] = v; __syncthreads();
  for (int off = 1; off < 256; off <<= 1){
    int t = (tid >= off) ? buf[tid - off] : 0;
    __syncthreads();
    buf[tid] += t;
    __syncthreads();
  }
  int excl = buf[tid] - v + boff[blockIdx.x];
  if (i < n){
    offs[i] = excl;
    cursor[i] = excl;
    if (i == n - 1) offs[n] = excl + v;
  }
}

// scatter writes (eid, src_combined) pairs so attention needs no edge gather
__global__ __launch_bounds__(256) void scatter_kernel(
    const int* __restrict__ edges, const int* __restrict__ ls_p,
    const int* __restrict__ ps_p, int* __restrict__ cursor,
    int2* __restrict__ sorted, int nlig, int E_,
    const int* __restrict__ flags)
{
  int e = blockIdx.x * 256 + threadIdx.x;
  if (e >= E_) return;
  int I64 = flags[1];
  int dl = edge_get(edges, I64, e, 0) - ls_p[0];
  int dp = edge_get(edges, I64, e, 1) - ps_p[0];
  int p1 = atomicAdd(&cursor[dl], 1);        sorted[p1] = make_int2(e, nlig + dp);
  int p2 = atomicAdd(&cursor[nlig + dp], 1); sorted[p2] = make_int2(e, dl);
}

// ---------------------------------------------------------------------------
// Attention over combined node space: one wave per destination node, online
// softmax. 64 lanes = 8 heads x 8 lanes; lane covers dims {2*lane, 2*lane+1}.
// Prefetches the next CSR entry to hide the index-load latency.
// ---------------------------------------------------------------------------
__global__ __launch_bounds__(256) void attn_kernel(
    const u16* __restrict__ Q, const u16* __restrict__ K, const u16* __restrict__ V,
    const int2* __restrict__ sorted, const int* __restrict__ offs,
    const float* __restrict__ ebias, u16* __restrict__ AGG, int ntot)
{
  int t = blockIdx.x * 4 + (threadIdx.x >> 6);
  if (t >= ntot) return;
  int lane = threadIdx.x & 63, h = lane >> 3;

  ushort2 qu = *(const ushort2*)&Q[(size_t)t * 128 + lane * 2];
  float q0 = bf2f(qu.x), q1 = bf2f(qu.y);

  int beg = offs[t], end = offs[t + 1];
  float m = -INFINITY, l = 0.f, a0 = 0.f, a1 = 0.f;

  int2 nxt = make_int2(0, 0);
  if (beg < end) nxt = sorted[beg];
  for (int i = beg; i < end; i++){
    int2 cur = nxt;
    if (i + 1 < end) nxt = sorted[i + 1];
    int src = cur.y;
    ushort2 ku = *(const ushort2*)&K[(size_t)src * 128 + lane * 2];
    ushort2 vu = *(const ushort2*)&V[(size_t)src * 128 + lane * 2];
    float eb = ebias[(size_t)cur.x * 8 + h];
    float part = q0 * bf2f(ku.x) + q1 * bf2f(ku.y);
    part += __shfl_xor(part, 1);
    part += __shfl_xor(part, 2);
    part += __shfl_xor(part, 4);            // per-head 16-dim dot done
    float logit = part * 0.25f + eb;        // SCALE = 16^-0.5
    float nm = fmaxf(m, logit);
    float alpha = __expf(m - nm);           // exp(-inf)=0 on first edge
    float p = __expf(logit - nm);
    a0 = a0 * alpha + p * bf2f(vu.x);
    a1 = a1 * alpha + p * bf2f(vu.y);
    l = l * alpha + p;
    m = nm;
  }
  float inv = 1.f / (l + 1e-8f);            // empty segment -> 0, matches ref
  ushort2 o; o.x = f2bf(a0 * inv); o.y = f2bf(a1 * inv);
  *(ushort2*)&AGG[(size_t)t * 128 + lane * 2] = o;
}

// ---------------------------------------------------------------------------
extern "C" void kernel_launch(void* const* d_in, const int* in_sizes, int n_in,
                              void* d_out, int out_size, void* d_ws, size_t ws_size,
                              hipStream_t stream)
{
  const void* ligand_x  = d_in[0];
  const void* protein_x = d_in[1];
  const int* edges      = (const int*)d_in[2];
  const void* attr      = d_in[3];
  const void* Wq = d_in[4];  const void* bq = d_in[5];
  const void* Wk = d_in[6];  const void* bk = d_in[7];
  const void* Wv = d_in[8];  const void* bv = d_in[9];
  const void* Wo = d_in[10]; const void* bo = d_in[11];
  const void* Wr = d_in[12]; const void* br = d_in[13];
  const int* ls_p = (const int*)d_in[14];
  const int* ps_p = (const int*)d_in[15];

  const int nlig = in_sizes[0] / 128;
  const int nprot = in_sizes[1] / 128;
  const int E = in_sizes[2] / 2;
  const int ntot = nlig + nprot;

  // workspace carve-up (256B aligned)
  char* w = (char*)d_ws;
  size_t off = 0;
  auto alloc = [&](size_t bytes) -> void* {
    void* p = w + off;
    off = (off + bytes + 255) & ~(size_t)255;
    return p;
  };
  int*   flags = (int*)alloc(256);
  u16*   Wt    = (u16*)alloc(4 * 16384 * 2);
  float* biasP = (float*)alloc(4 * 128 * 4);
  u16* Qb  = (u16*)alloc((size_t)ntot * 128 * 2);
  u16* Kb  = (u16*)alloc((size_t)ntot * 128 * 2);
  u16* Vb  = (u16*)alloc((size_t)ntot * 128 * 2);
  u16* AGG = (u16*)alloc((size_t)ntot * 128 * 2);
  float* ebias = (float*)alloc((size_t)E * 8 * 4);
  int* cnt    = (int*)alloc((size_t)ntot * 4);
  int* offs   = (int*)alloc((size_t)(ntot + 1) * 4);
  int* cursor = (int*)alloc((size_t)ntot * 4);
  int* bsum   = (int*)alloc(512 * 4);
  int* boff   = (int*)alloc(512 * 4);
  int2* sorted = (int2*)alloc((size_t)2 * E * 8);
  (void)ws_size; (void)n_in; (void)out_size;

  const int mb_l = (nlig + 63) / 64;
  const int mb_p = (nprot + 63) / 64;
  const int mb_t = (ntot + 63) / 64;
  const int eb = (E + 255) / 256;
  const int nb = (ntot + 255) / 256;

  // 0. dtype detection + weight prep
  detect_kernel<<<1, 64, 0, stream>>>((const u16*)ligand_x, edges, flags);
  prep_w<<<4, 256, 0, stream>>>(Wq, Wk, Wv, Wo, bq, bk, bv, bo, Wt, biasP, flags);

  // 1. fused q/k/v projection over both node sets -> combined Q/K/V
  gemm_multi<<<mb_l + mb_p, 256, 0, stream>>>(
      ligand_x, nlig, protein_x, nprot, mb_l,
      Wt, biasP, /*wbase=*/0, /*nm=*/3,
      Qb, Kb, Vb, nullptr, /*a_force_bf16=*/0, /*final=*/0, flags);

  // 2. rbf bias
  rbf_kernel<<<eb, 256, 0, stream>>>(attr, Wr, br, ebias, E, flags);

  // 3. CSR build
  hipMemsetAsync(cnt, 0, (size_t)ntot * 4, stream);
  count_kernel<<<eb, 256, 0, stream>>>(edges, ls_p, ps_p, cnt, nlig, E, flags);
  scan_blocksum<<<nb, 256, 0, stream>>>(cnt, bsum, ntot);
  scan_bsum<<<1, 512, 0, stream>>>(bsum, boff, nb);
  scan_final<<<nb, 256, 0, stream>>>(cnt, boff, offs, cursor, ntot);
  scatter_kernel<<<eb, 256, 0, stream>>>(edges, ls_p, ps_p, cursor, sorted, nlig, E, flags);

  // 4. attention (one wave per destination node, combined space)
  attn_kernel<<<(ntot + 3) / 4, 256, 0, stream>>>(Qb, Kb, Vb, sorted, offs, ebias, AGG, ntot);

  // 5. output projection: AGG[ntot] @ Wo + bo -> d_out (fp32 per flags)
  gemm_multi<<<mb_t, 256, 0, stream>>>(
      AGG, ntot, nullptr, 0, mb_t,
      Wt, biasP, /*wbase=*/3, /*nm=*/1,
      (u16*)d_out, nullptr, nullptr, (float*)d_out,
      /*a_force_bf16=*/1, /*final=*/1, flags);
}

// Round 5
// 340.520 us; speedup vs baseline: 1.2240x; 1.1112x over previous
//
#include <hip/hip_runtime.h>
#include <hip/hip_bf16.h>

typedef unsigned short u16;
typedef __attribute__((ext_vector_type(8))) short short8;
typedef __attribute__((ext_vector_type(4))) float f32x4;

__device__ __forceinline__ float bf2f(u16 u){
  union { unsigned int i; float f; } c; c.i = ((unsigned int)u) << 16; return c.f;
}
__device__ __forceinline__ u16 f2bf(float f){
  union { float f; unsigned int i; } c; c.f = f;
  unsigned int x = c.i;
  return (u16)((x + 0x7FFFu + ((x >> 16) & 1u)) >> 16);  // RNE
}

// int64-aware edge fetch (values < 2^31, little-endian: low word is the value)
__device__ __forceinline__ int edge_get(const int* __restrict__ e32, int i64, int e, int c){
  int idx = 2 * e + c;
  return i64 ? e32[2 * idx] : e32[idx];
}

// ---------------------------------------------------------------------------
// Dtype detection (R1/R2 evidence: inputs ARE fp32; kept as insurance).
// flags[0]=1 -> float inputs fp32 (else bf16); flags[1]=1 -> edges int64.
// ---------------------------------------------------------------------------
__global__ void detect_kernel(const u16* __restrict__ lig16,
                              const int* __restrict__ e32, int* __restrict__ flags)
{
  int lane = threadIdx.x;
  int cnt = 0, nz = 0;
  #pragma unroll
  for (int j = 0; j < 4; j++){
    u16 u = lig16[(lane * 4 + j) * 2];
    int ex = (u >> 7) & 0xFF;
    if (ex >= 96 && ex < 160) cnt++;
    if (e32[(lane * 4 + j) * 2 + 1] != 0) nz++;
  }
  #pragma unroll
  for (int off = 1; off < 64; off <<= 1){
    cnt += __shfl_xor(cnt, off);
    nz  += __shfl_xor(nz, off);
  }
  if (lane == 0){
    flags[0] = (cnt < 128) ? 1 : 0;
    flags[1] = (nz == 0) ? 1 : 0;
  }
}

// ---------------------------------------------------------------------------
// prep_w: Wt[mat][n][k] = bf16(W[mat][k][n]) for Wq,Wk,Wv,Wo; biases -> fp32.
// ---------------------------------------------------------------------------
__global__ __launch_bounds__(256) void prep_w(
    const void* __restrict__ Wq, const void* __restrict__ Wk,
    const void* __restrict__ Wv, const void* __restrict__ Wo,
    const void* __restrict__ bq, const void* __restrict__ bk,
    const void* __restrict__ bv, const void* __restrict__ bo,
    u16* __restrict__ Wt, float* __restrict__ biasP, const int* __restrict__ flags)
{
  int mat = blockIdx.x, tid = threadIdx.x;
  const void* W = (mat == 0) ? Wq : (mat == 1) ? Wk : (mat == 2) ? Wv : Wo;
  const void* b = (mat == 0) ? bq : (mat == 1) ? bk : (mat == 2) ? bv : bo;
  int F = flags[0];
  u16* dst = Wt + mat * 16384;
  #pragma unroll 4
  for (int j = 0; j < 64; j++){
    int idx = tid + j * 256;            // k = idx>>7, n = idx&127
    u16 w = F ? f2bf(((const float*)W)[idx]) : ((const u16*)W)[idx];
    dst[(idx & 127) * 128 + (idx >> 7)] = w;
  }
  if (tid < 128)
    biasP[mat * 128 + tid] = F ? ((const float*)b)[tid] : bf2f(((const u16*)b)[tid]);
}

// ---------------------------------------------------------------------------
// gemm_multi: two input regions x nm weight mats, MFMA 16x16x32 bf16,
// 64x128 tile. Epilogue staged through LDS (fp32, padded stride 132) then
// coalesced 16B stores — R4's 96 scalar 2B stores/thread were the 82 µs
// bottleneck (store-issue bound, all pipes <16%).
// ---------------------------------------------------------------------------
__global__ __launch_bounds__(256) void gemm_multi(
    const void* __restrict__ A0, int M0, const void* __restrict__ A1, int M1, int mb0,
    const u16* __restrict__ Wt, const float* __restrict__ biasP, int wbase, int nm,
    u16* __restrict__ O0b, u16* __restrict__ O1b, u16* __restrict__ O2b,
    float* __restrict__ O0f,
    int a_force_bf16, int final_out, const int* __restrict__ flags)
{
  __shared__ __align__(16) char smem[52224];
  u16 (*As)[136]  = (u16(*)[136])smem;             // 64*136*2  = 17408 B
  u16 (*Ws)[136]  = (u16(*)[136])(smem + 17408);   // 128*136*2 = 34816 B
  float (*Fs)[132] = (float(*)[132])(smem + 17408); // reuse: 64*132*4 = 33792 B

  int tid = threadIdx.x;
  int F = flags[0];
  int AF = a_force_bf16 ? 0 : F;       // A dtype: 1=fp32, 0=bf16
  int xb = blockIdx.x;
  const void* A; int M, m0, orow;
  if (xb < mb0){ A = A0; M = M0; m0 = xb * 64;          orow = m0; }
  else         { A = A1; M = M1; m0 = (xb - mb0) * 64;  orow = M0 + m0; }

  // Stage A tile (64 x 128)
  if (AF){
    const float* Af = (const float*)A;
    #pragma unroll
    for (int j = 0; j < 8; j++){
      int idx = tid + j * 256;
      int m = idx >> 5, k4 = idx & 31;
      float4 v = make_float4(0.f, 0.f, 0.f, 0.f);
      if (m0 + m < M) v = *(const float4*)&Af[(size_t)(m0 + m) * 128 + k4 * 4];
      ushort4 o; o.x = f2bf(v.x); o.y = f2bf(v.y); o.z = f2bf(v.z); o.w = f2bf(v.w);
      *(ushort4*)&As[m][k4 * 4] = o;
    }
  } else {
    const u16* Au = (const u16*)A;
    #pragma unroll
    for (int j = 0; j < 8; j++){
      int idx = tid + j * 256;
      int m = idx >> 5, k4 = idx & 31;
      ushort4 v = make_ushort4(0, 0, 0, 0);
      if (m0 + m < M) v = *(const ushort4*)&Au[(size_t)(m0 + m) * 128 + k4 * 4];
      *(ushort4*)&As[m][k4 * 4] = v;
    }
  }
  // Stage Wt[wbase]
  {
    const u16* Wsrc = Wt + (size_t)wbase * 16384;
    #pragma unroll
    for (int j = 0; j < 8; j++){
      int idx = tid + j * 256;
      *(short8*)&Ws[idx >> 4][(idx & 15) * 8] = *(const short8*)&Wsrc[idx * 8];
    }
  }
  __syncthreads();

  int wave = tid >> 6, lane = tid & 63;
  int quad = lane >> 4, ml = lane & 15;

  short8 af[4];
  #pragma unroll
  for (int kk = 0; kk < 4; kk++)
    af[kk] = *(const short8*)&As[wave * 16 + ml][kk * 32 + quad * 8];

  int f32out = final_out && F;

  for (int mat = 0; mat < nm; mat++){
    f32x4 acc[8];
    #pragma unroll
    for (int nt = 0; nt < 8; nt++) acc[nt] = (f32x4){0.f, 0.f, 0.f, 0.f};

    #pragma unroll
    for (int nt = 0; nt < 8; nt++){
      #pragma unroll
      for (int kk = 0; kk < 4; kk++){
        short8 bfr = *(const short8*)&Ws[nt * 16 + ml][kk * 32 + quad * 8];
        acc[nt] = __builtin_amdgcn_mfma_f32_16x16x32_bf16(af[kk], bfr, acc[nt], 0, 0, 0);
      }
    }

    __syncthreads();                    // everyone done reading Ws
    // stage acc+bias as fp32 into Fs (2-way bank aliasing only: free)
    const float* bp = biasP + (size_t)(wbase + mat) * 128;
    #pragma unroll
    for (int nt = 0; nt < 8; nt++){
      float bcol = bp[nt * 16 + ml];
      #pragma unroll
      for (int r = 0; r < 4; r++)
        Fs[wave * 16 + quad * 4 + r][nt * 16 + ml] = acc[nt][r] + bcol;
    }
    __syncthreads();

    // coalesced global stores from Fs
    if (f32out){
      #pragma unroll
      for (int j = 0; j < 8; j++){
        int u = tid + j * 256;          // 2048 float4 units
        int row = u >> 5, c4 = (u & 31) * 4;
        if (m0 + row < M)
          *(float4*)&O0f[(size_t)(orow + row) * 128 + c4] = *(const float4*)&Fs[row][c4];
      }
    } else {
      u16* Cb = (mat == 0) ? O0b : ((mat == 1) ? O1b : O2b);
      #pragma unroll
      for (int j = 0; j < 4; j++){
        int u = tid + j * 256;          // 1024 x 8-col units
        int row = u >> 4, c8 = (u & 15) * 8;
        if (m0 + row < M){
          float4 x = *(const float4*)&Fs[row][c8];
          float4 y = *(const float4*)&Fs[row][c8 + 4];
          short8 s8;
          s8[0] = (short)f2bf(x.x); s8[1] = (short)f2bf(x.y);
          s8[2] = (short)f2bf(x.z); s8[3] = (short)f2bf(x.w);
          s8[4] = (short)f2bf(y.x); s8[5] = (short)f2bf(y.y);
          s8[6] = (short)f2bf(y.z); s8[7] = (short)f2bf(y.w);
          *(short8*)&Cb[(size_t)(orow + row) * 128 + c8] = s8;
        }
      }
    }

    if (mat + 1 < nm){
      __syncthreads();                  // done reading Fs (aliases Ws)
      const u16* Wsrc = Wt + (size_t)(wbase + mat + 1) * 16384;
      #pragma unroll
      for (int j = 0; j < 8; j++){
        int idx = tid + j * 256;
        *(short8*)&Ws[idx >> 4][(idx & 15) * 8] = *(const short8*)&Wsrc[idx * 8];
      }
      __syncthreads();
    }
  }
}

// ---------------------------------------------------------------------------
// edge_pre: fused RBF bias (ebias[E,8] = attr@Wr + br) + degree count.
// ---------------------------------------------------------------------------
__global__ __launch_bounds__(256) void edge_pre(
    const void* __restrict__ attr, const void* __restrict__ Wr,
    const void* __restrict__ br, float* __restrict__ ebias,
    const int* __restrict__ edges, const int* __restrict__ ls_p,
    const int* __restrict__ ps_p, int* __restrict__ cnt, int nlig, int E_,
    const int* __restrict__ flags)
{
  __shared__ float w[16][8];
  __shared__ float b[8];
  int tid = threadIdx.x;
  int F = flags[0];
  if (tid < 128) w[tid >> 3][tid & 7] = F ? ((const float*)Wr)[tid] : bf2f(((const u16*)Wr)[tid]);
  if (tid < 8)   b[tid] = F ? ((const float*)br)[tid] : bf2f(((const u16*)br)[tid]);
  __syncthreads();
  int e = blockIdx.x * 256 + tid;
  if (e >= E_) return;

  int I64 = flags[1];
  int dl = edge_get(edges, I64, e, 0) - ls_p[0];
  int dp = edge_get(edges, I64, e, 1) - ps_p[0];
  atomicAdd(&cnt[dl], 1);
  atomicAdd(&cnt[nlig + dp], 1);

  float a[16];
  if (F){
    const float* af = (const float*)attr;
    #pragma unroll
    for (int j = 0; j < 4; j++){
      float4 t = *(const float4*)&af[e * 16 + j * 4];
      a[4*j] = t.x; a[4*j+1] = t.y; a[4*j+2] = t.z; a[4*j+3] = t.w;
    }
  } else {
    const u16* au = (const u16*)attr;
    #pragma unroll
    for (int j = 0; j < 4; j++){
      ushort4 t = *(const ushort4*)&au[e * 16 + j * 4];
      a[4*j] = bf2f(t.x); a[4*j+1] = bf2f(t.y); a[4*j+2] = bf2f(t.z); a[4*j+3] = bf2f(t.w);
    }
  }
  #pragma unroll
  for (int hh = 0; hh < 8; hh++){
    float s = b[hh];
    #pragma unroll
    for (int r = 0; r < 16; r++) s += a[r] * w[r][hh];
    ebias[e * 8 + hh] = s;
  }
}

// ---------------------------------------------------------------------------
// Scan (3 small kernels) + scatter of (eid, src_combined) pairs.
// ---------------------------------------------------------------------------
__global__ __launch_bounds__(256) void scan_blocksum(
    const int* __restrict__ cnt, int* __restrict__ bsum, int n)
{
  __shared__ int red[4];
  int tid = threadIdx.x;
  int i = blockIdx.x * 256 + tid;
  int v = (i < n) ? cnt[i] : 0;
  #pragma unroll
  for (int off = 1; off < 64; off <<= 1) v += __shfl_xor(v, off);
  if ((tid & 63) == 0) red[tid >> 6] = v;
  __syncthreads();
  if (tid == 0) bsum[blockIdx.x] = red[0] + red[1] + red[2] + red[3];
}

__global__ __launch_bounds__(512) void scan_bsum(
    int* __restrict__ bsum, int* __restrict__ boff, int nb)
{
  __shared__ int buf[512];
  int tid = threadIdx.x;
  int v = (tid < nb) ? bsum[tid] : 0;
  buf[tid] = v; __syncthreads();
  for (int off = 1; off < 512; off <<= 1){
    int t = (tid >= off) ? buf[tid - off] : 0;
    __syncthreads();
    buf[tid] += t;
    __syncthreads();
  }
  if (tid < nb) boff[tid] = buf[tid] - v;   // exclusive
}

__global__ __launch_bounds__(256) void scan_final(
    const int* __restrict__ cnt, const int* __restrict__ boff,
    int* __restrict__ offs, int* __restrict__ cursor, int n)
{
  __shared__ int buf[256];
  int tid = threadIdx.x;
  int i = blockIdx.x * 256 + tid;
  int v = (i < n) ? cnt[i] : 0;
  buf[tid] = v; __syncthreads();
  for (int off = 1; off < 256; off <<= 1){
    int t = (tid >= off) ? buf[tid - off] : 0;
    __syncthreads();
    buf[tid] += t;
    __syncthreads();
  }
  int excl = buf[tid] - v + boff[blockIdx.x];
  if (i < n){
    offs[i] = excl;
    cursor[i] = excl;
    if (i == n - 1) offs[n] = excl + v;
  }
}

__global__ __launch_bounds__(256) void scatter_kernel(
    const int* __restrict__ edges, const int* __restrict__ ls_p,
    const int* __restrict__ ps_p, int* __restrict__ cursor,
    int2* __restrict__ sorted, int nlig, int E_,
    const int* __restrict__ flags)
{
  int e = blockIdx.x * 256 + threadIdx.x;
  if (e >= E_) return;
  int I64 = flags[1];
  int dl = edge_get(edges, I64, e, 0) - ls_p[0];
  int dp = edge_get(edges, I64, e, 1) - ps_p[0];
  int p1 = atomicAdd(&cursor[dl], 1);        sorted[p1] = make_int2(e, nlig + dp);
  int p2 = atomicAdd(&cursor[nlig + dp], 1); sorted[p2] = make_int2(e, dl);
}

// ---------------------------------------------------------------------------
// Attention over combined node space: one wave per destination node, online
// softmax. 64 lanes = 8 heads x 8 lanes; lane covers dims {2*lane, 2*lane+1}.
// ---------------------------------------------------------------------------
__global__ __launch_bounds__(256) void attn_kernel(
    const u16* __restrict__ Q, const u16* __restrict__ K, const u16* __restrict__ V,
    const int2* __restrict__ sorted, const int* __restrict__ offs,
    const float* __restrict__ ebias, u16* __restrict__ AGG, int ntot)
{
  int t = blockIdx.x * 4 + (threadIdx.x >> 6);
  if (t >= ntot) return;
  int lane = threadIdx.x & 63, h = lane >> 3;

  ushort2 qu = *(const ushort2*)&Q[(size_t)t * 128 + lane * 2];
  float q0 = bf2f(qu.x), q1 = bf2f(qu.y);

  int beg = offs[t], end = offs[t + 1];
  float m = -INFINITY, l = 0.f, a0 = 0.f, a1 = 0.f;

  int2 nxt = make_int2(0, 0);
  if (beg < end) nxt = sorted[beg];
  for (int i = beg; i < end; i++){
    int2 cur = nxt;
    if (i + 1 < end) nxt = sorted[i + 1];
    int src = cur.y;
    ushort2 ku = *(const ushort2*)&K[(size_t)src * 128 + lane * 2];
    ushort2 vu = *(const ushort2*)&V[(size_t)src * 128 + lane * 2];
    float eb = ebias[(size_t)cur.x * 8 + h];
    float part = q0 * bf2f(ku.x) + q1 * bf2f(ku.y);
    part += __shfl_xor(part, 1);
    part += __shfl_xor(part, 2);
    part += __shfl_xor(part, 4);            // per-head 16-dim dot done
    float logit = part * 0.25f + eb;        // SCALE = 16^-0.5
    float nm = fmaxf(m, logit);
    float alpha = __expf(m - nm);           // exp(-inf)=0 on first edge
    float p = __expf(logit - nm);
    a0 = a0 * alpha + p * bf2f(vu.x);
    a1 = a1 * alpha + p * bf2f(vu.y);
    l = l * alpha + p;
    m = nm;
  }
  float inv = 1.f / (l + 1e-8f);            // empty segment -> 0, matches ref
  ushort2 o; o.x = f2bf(a0 * inv); o.y = f2bf(a1 * inv);
  *(ushort2*)&AGG[(size_t)t * 128 + lane * 2] = o;
}

// ---------------------------------------------------------------------------
extern "C" void kernel_launch(void* const* d_in, const int* in_sizes, int n_in,
                              void* d_out, int out_size, void* d_ws, size_t ws_size,
                              hipStream_t stream)
{
  const void* ligand_x  = d_in[0];
  const void* protein_x = d_in[1];
  const int* edges      = (const int*)d_in[2];
  const void* attr      = d_in[3];
  const void* Wq = d_in[4];  const void* bq = d_in[5];
  const void* Wk = d_in[6];  const void* bk = d_in[7];
  const void* Wv = d_in[8];  const void* bv = d_in[9];
  const void* Wo = d_in[10]; const void* bo = d_in[11];
  const void* Wr = d_in[12]; const void* br = d_in[13];
  const int* ls_p = (const int*)d_in[14];
  const int* ps_p = (const int*)d_in[15];

  const int nlig = in_sizes[0] / 128;
  const int nprot = in_sizes[1] / 128;
  const int E = in_sizes[2] / 2;
  const int ntot = nlig + nprot;

  char* w = (char*)d_ws;
  size_t off = 0;
  auto alloc = [&](size_t bytes) -> void* {
    void* p = w + off;
    off = (off + bytes + 255) & ~(size_t)255;
    return p;
  };
  int*   flags = (int*)alloc(256);
  u16*   Wt    = (u16*)alloc(4 * 16384 * 2);
  float* biasP = (float*)alloc(4 * 128 * 4);
  u16* Qb  = (u16*)alloc((size_t)ntot * 128 * 2);
  u16* Kb  = (u16*)alloc((size_t)ntot * 128 * 2);
  u16* Vb  = (u16*)alloc((size_t)ntot * 128 * 2);
  u16* AGG = (u16*)alloc((size_t)ntot * 128 * 2);
  float* ebias = (float*)alloc((size_t)E * 8 * 4);
  int* cnt    = (int*)alloc((size_t)ntot * 4);
  int* offs   = (int*)alloc((size_t)(ntot + 1) * 4);
  int* cursor = (int*)alloc((size_t)ntot * 4);
  int* bsum   = (int*)alloc(512 * 4);
  int* boff   = (int*)alloc(512 * 4);
  int2* sorted = (int2*)alloc((size_t)2 * E * 8);
  (void)ws_size; (void)n_in; (void)out_size;

  const int mb_l = (nlig + 63) / 64;
  const int mb_p = (nprot + 63) / 64;
  const int mb_t = (ntot + 63) / 64;
  const int eb = (E + 255) / 256;
  const int nb = (ntot + 255) / 256;

  // 0. memset + detection + weight prep
  hipMemsetAsync(cnt, 0, (size_t)ntot * 4, stream);
  detect_kernel<<<1, 64, 0, stream>>>((const u16*)ligand_x, edges, flags);
  prep_w<<<4, 256, 0, stream>>>(Wq, Wk, Wv, Wo, bq, bk, bv, bo, Wt, biasP, flags);

  // 1. fused q/k/v projection over both node sets -> combined Q/K/V
  gemm_multi<<<mb_l + mb_p, 256, 0, stream>>>(
      ligand_x, nlig, protein_x, nprot, mb_l,
      Wt, biasP, /*wbase=*/0, /*nm=*/3,
      Qb, Kb, Vb, nullptr, /*a_force_bf16=*/0, /*final=*/0, flags);

  // 2. fused rbf bias + degree count
  edge_pre<<<eb, 256, 0, stream>>>(attr, Wr, br, ebias, edges, ls_p, ps_p,
                                   cnt, nlig, E, flags);

  // 3. scan + scatter
  scan_blocksum<<<nb, 256, 0, stream>>>(cnt, bsum, ntot);
  scan_bsum<<<1, 512, 0, stream>>>(bsum, boff, nb);
  scan_final<<<nb, 256, 0, stream>>>(cnt, boff, offs, cursor, ntot);
  scatter_kernel<<<eb, 256, 0, stream>>>(edges, ls_p, ps_p, cursor, sorted, nlig, E, flags);

  // 4. attention (one wave per destination node, combined space)
  attn_kernel<<<(ntot + 3) / 4, 256, 0, stream>>>(Qb, Kb, Vb, sorted, offs, ebias, AGG, ntot);

  // 5. output projection: AGG[ntot] @ Wo + bo -> d_out (fp32 per flags)
  gemm_multi<<<mb_t, 256, 0, stream>>>(
      AGG, ntot, nullptr, 0, mb_t,
      Wt, biasP, /*wbase=*/3, /*nm=*/1,
      (u16*)d_out, nullptr, nullptr, (float*)d_out,
      /*a_force_bf16=*/1, /*final=*/1, flags);
}